// Round 10
// baseline (154.253 us; speedup 1.0000x reference)
//
#include <hip/hip_runtime.h>
#include <hip/hip_bf16.h>

// ---------------------------------------------------------------------------
// NaiveFourierKANLayer as GEMM:  y = [cos|sin features][4096 x 32768] * W + b
// R10: R9 (512x128 tile, 8 waves, splitK=16, B dbuf via global_load_lds, bf16
// partials) + de-phase-locked A-synthesis:
//   - seeds (sin/cos + doubling ladder) for iter ii+1 computed between MFMA
//     s-groups 0 and 1 of iter ii  -> hidden under 96 MFMAs of matrix time
//   - chain8 recurrences moved inside the s-loop -> hidden per-s under MFMAs
// Seeds = 7 floats x 4 rf x 2 bufs = 56 VGPR; total ~250 (stay under the 256
// cliff so 2 waves/SIMD survive). Per-harmonic math identical to R5-R9.
// ---------------------------------------------------------------------------

typedef __attribute__((ext_vector_type(8))) short short8;
typedef __attribute__((ext_vector_type(4))) float f32x4;

#define SPLITK 16
#define ICHUNK (256 / SPLITK)   // 16 i's per block

#define INV2PI 0.15915494309189535f

// ---- bf16 pack helpers ----
__device__ __forceinline__ unsigned short f2bf(float f) {
    unsigned u = __builtin_bit_cast(unsigned, f);
    u += 0x7fffu + ((u >> 16) & 1u);
    return (unsigned short)(u >> 16);
}
#if __has_builtin(__builtin_amdgcn_cvt_pk_bf16_f32)
typedef __attribute__((ext_vector_type(2))) __bf16 bf16x2_t;
__device__ __forceinline__ unsigned pkbf16(float a, float b) {
    bf16x2_t v = __builtin_amdgcn_cvt_pk_bf16_f32(a, b);
    return __builtin_bit_cast(unsigned, v);
}
#else
__device__ __forceinline__ unsigned pkbf16(float a, float b) {
    unsigned ua = __builtin_bit_cast(unsigned, a) + 0x8000u;
    unsigned ub = __builtin_bit_cast(unsigned, b) + 0x8000u;
    return __builtin_amdgcn_perm(ub, ua, 0x07060302u);  // [b.hi16 | a.hi16]
}
#endif

__device__ __forceinline__ void dbl2(float c, float s, float& co, float& so) {
    float t = c + c;
    co = __builtin_fmaf(t, c, -1.f);
    so = t * s;
}
__device__ __forceinline__ void rot2(float c, float s, float cr, float sr,
                                     float& co, float& so) {
    float t = s * sr;
    co = __builtin_fmaf(c, cr, -t);
    float u = s * cr;
    so = __builtin_fmaf(c, sr, u);
}

// 8 consecutive harmonics from seeds f_{-1}, f_0 with multiplier m1=2cos(x)
__device__ __forceinline__ short8 chain8(float m1, float fm1, float f0) {
    unsigned r[4];
    float vp = fm1, v = f0;
    #pragma unroll
    for (int h = 0; h < 4; ++h) {
        float v1 = __builtin_fmaf(m1, v, -vp);
        r[h] = pkbf16(v, v1);
        float v2 = __builtin_fmaf(m1, v1, -v);
        vp = v1; v = v2;
    }
    uint4 u; u.x = r[0]; u.y = r[1]; u.z = r[2]; u.w = r[3];
    return __builtin_bit_cast(short8, u);
}

// async 16B global->LDS
__device__ __forceinline__ void async_load16(const void* g, void* l) {
    __builtin_amdgcn_global_load_lds(
        (const __attribute__((address_space(1))) unsigned int*)g,
        (__attribute__((address_space(3))) unsigned int*)l,
        16, 0, 0);
}

// per-row seed set: enough to rebuild all 4 k-step fragments
struct Seed {
    float m1, cq, sq, c1, s1, c32, s32;
};

// ---------------------------------------------------------------------------
// prep kernel (bid' = bid + base): [0,4096) convert fc -> ws2 image order
// (one 16B granule per thread); [4096,5120) init out = bias (atomic fallback).
// ---------------------------------------------------------------------------
__global__ __launch_bounds__(256) void prep_kernel(
    const float* __restrict__ fc, const float* __restrict__ bias,
    unsigned short* __restrict__ ws2, float* __restrict__ out, int base)
{
    const unsigned bid = blockIdx.x + base;
    const unsigned t = threadIdx.x;
    if (bid < 4096) {
        unsigned flat = bid * 256 + t;                // 0 .. 2^20-1
        unsigned bx = flat >> 11, gi = flat & 2047;
        unsigned i = bx >> 1, y = bx & 1;
        unsigned sog = gi >> 6, ll = gi & 63;
        unsigned s = sog >> 3, og = sog & 7;
        unsigned op = og * 16 + (ll & 15);
        unsigned k = s * 32 + ((ll >> 4) * 8);
        unsigned tt = k >> 6, g0 = k & 63;
        const float4* src = (const float4*)(fc +
            ((((size_t)tt * 256 + y * 128 + op) * 256 + i) * 64 + g0));
        float4 a = src[0], b = src[1];
        uint4 v;
        v.x = pkbf16(a.x, a.y); v.y = pkbf16(a.z, a.w);
        v.z = pkbf16(b.x, b.y); v.w = pkbf16(b.z, b.w);
        ((uint4*)ws2)[flat] = v;
    } else {
        int tid = (bid - 4096) * 256 + t;             // 0..262143
        float4 b4 = ((const float4*)bias)[tid & 63];
        ((float4*)out)[tid] = b4;
    }
}

// out = bias + sum_z bf16partial[z]
__global__ __launch_bounds__(256) void reduce_kernel(
    const unsigned short* __restrict__ pws, const float* __restrict__ bias,
    float* __restrict__ out)
{
    int idx4 = blockIdx.x * 256 + threadIdx.x;        // 0..262143 float4s
    float4 r = ((const float4*)bias)[idx4 & 63];
    #pragma unroll
    for (int z = 0; z < SPLITK; ++z) {
        ushort4 v = ((const ushort4*)pws)[(size_t)z * 262144 + idx4];
        r.x += __builtin_bit_cast(float, (unsigned)v.x << 16);
        r.y += __builtin_bit_cast(float, (unsigned)v.y << 16);
        r.z += __builtin_bit_cast(float, (unsigned)v.z << 16);
        r.w += __builtin_bit_cast(float, (unsigned)v.w << 16);
    }
    ((float4*)out)[idx4] = r;
}

template <bool USE_WS, bool PARTIAL>
__global__ __launch_bounds__(512, 2) void fkan_gemm(
    const float* __restrict__ x, const float* __restrict__ fc,
    const unsigned short* __restrict__ bws, float* __restrict__ out,
    unsigned short* __restrict__ pws)
{
    __shared__ uint4 Bimg[2][2048];        // 64 KB: coeff image, double-buffered
    __shared__ float xs[ICHUNK][512];      // 32 KB: x[i][row] transposed

    const int t  = threadIdx.x;            // 0..511
    const int l  = t & 63;
    const int w  = t >> 6;                 // row-wave 0..7 (64 rows each)
    const int q  = l >> 4;                 // MFMA quad -> k offset 8q
    const int m  = l & 15;                 // MFMA row within 16

    const int bid = blockIdx.x;
    const int z   = bid & 15;
    const int by  = (bid >> 4) & 1;
    const int bx  = bid >> 5;
    const int rowBase = bx * 512;
    const int iBase   = z * ICHUNK;

    f32x4 acc[4][8];
    #pragma unroll
    for (int a = 0; a < 4; ++a)
        #pragma unroll
        for (int b = 0; b < 8; ++b) acc[a][b] = (f32x4)0.0f;

    auto stageB = [&](int p, int i) {
        if (USE_WS) {
            const uint4* base = (const uint4*)bws + (size_t)(i * 2 + by) * 2048;
            #pragma unroll
            for (int cc = 0; cc < 4; ++cc) {
                int c = cc * 8 + w;                 // wave-uniform chunk id
                async_load16(base + (size_t)c * 64 + l, (void*)(&Bimg[p][c * 64]));
            }
        } else {
            #pragma unroll
            for (int gg = 0; gg < 4; ++gg) {
                int gi  = gg * 512 + t;
                int sog = gi >> 6, ll = gi & 63;
                int s = sog >> 3, ogb = sog & 7;
                int o = ogb * 16 + (ll & 15);
                int k = s * 32 + (ll >> 4) * 8;
                int tt = k >> 6, g = k & 63;
                const float4* p4 = (const float4*)(fc +
                    ((((size_t)tt * 256 + by * 128 + o) * 256 + i) * 64 + g));
                float4 a = p4[0], b = p4[1];
                uint4 v;
                v.x = pkbf16(a.x, a.y); v.y = pkbf16(a.z, a.w);
                v.z = pkbf16(b.x, b.y); v.w = pkbf16(b.z, b.w);
                Bimg[p][gi] = v;
            }
        }
    };

    // seeds for one iteration (4 rf rows per lane); math identical to R5-R9
    auto computeSeeds = [&](int ii, Seed sd[4]) {
        #pragma unroll
        for (int rf = 0; rf < 4; ++rf) {
            float xv = xs[ii][w * 64 + rf * 16 + m];
            float rev = xv * INV2PI;
            float s1 = __builtin_amdgcn_sinf(rev);
            float c1 = __builtin_amdgcn_cosf(rev);
            const float m1 = c1 + c1;
            float c2, s2, c4, s4, c8, s8, c16, s16, c32, s32;
            dbl2(c1, s1, c2, s2);
            dbl2(c2, s2, c4, s4);
            dbl2(c4, s4, c8, s8);
            dbl2(c8, s8, c16, s16);
            dbl2(c16, s16, c32, s32);
            float c24, s24;
            rot2(c16, s16, c8, s8, c24, s24);
            float cq = (q == 0) ? 1.f : (q == 1) ? c8 : (q == 2) ? c16 : c24;
            float sq = (q == 0) ? 0.f : (q == 1) ? s8 : (q == 2) ? s16 : s24;
            sd[rf].m1 = m1; sd[rf].cq = cq; sd[rf].sq = sq;
            sd[rf].c1 = c1; sd[rf].s1 = s1;
            sd[rf].c32 = c32; sd[rf].s32 = s32;
        }
    };

    // build fragment for (rf, s) from seeds: same op sequence as R5's unrolled code
    auto makeA = [&](const Seed& sd, int s) -> short8 {
        float fm1, f0;
        if (s == 0) {
            fm1 = sd.cq;
            f0  = __builtin_fmaf(sd.cq, sd.c1, -(sd.sq * sd.s1));        // cq1
        } else if (s == 1) {
            float cB, sB;
            rot2(sd.cq, sd.sq, sd.c32, sd.s32, cB, sB);                  // 8q+32
            fm1 = cB;
            f0  = __builtin_fmaf(cB, sd.c1, -(sB * sd.s1));              // cB1
        } else if (s == 2) {
            fm1 = sd.sq;
            f0  = __builtin_fmaf(sd.cq, sd.s1, sd.sq * sd.c1);           // sq1
        } else {
            float cB, sB;
            rot2(sd.cq, sd.sq, sd.c32, sd.s32, cB, sB);
            fm1 = sB;
            f0  = __builtin_fmaf(cB, sd.s1, sB * sd.c1);                 // sB1
        }
        return chain8(sd.m1, fm1, f0);
    };

    // ---- preamble: stage B(iter0) + x tile, one barrier, seeds(iter0) ----
    stageB(0, iBase);
    {
        const float4* px = (const float4*)(x + (size_t)(rowBase + t) * 256 + iBase);
        #pragma unroll
        for (int j4 = 0; j4 < 4; ++j4) {
            float4 v = px[j4];
            xs[j4 * 4 + 0][t] = v.x;
            xs[j4 * 4 + 1][t] = v.y;
            xs[j4 * 4 + 2][t] = v.z;
            xs[j4 * 4 + 3][t] = v.w;
        }
    }
    __syncthreads();

    Seed sdC[4], sdN[4];
    computeSeeds(0, sdC);

    #pragma unroll 1
    for (int ii = 0; ii < ICHUNK; ++ii) {
        const int p = ii & 1;

        // 1. async-stage next B into the other buffer
        if (ii + 1 < ICHUNK) stageB(p ^ 1, iBase + ii + 1);

        // 2. s=0 group: chains + 32 MFMAs (gives matrix pipe a head start)
        {
            short8 bF[8];
            #pragma unroll
            for (int cf = 0; cf < 8; ++cf)
                bF[cf] = __builtin_bit_cast(short8, Bimg[p][(0 * 8 + cf) * 64 + l]);
            short8 aF[4];
            #pragma unroll
            for (int rf = 0; rf < 4; ++rf) aF[rf] = makeA(sdC[rf], 0);
            #pragma unroll
            for (int rf = 0; rf < 4; ++rf)
                #pragma unroll
                for (int cf = 0; cf < 8; ++cf)
                    acc[rf][cf] = __builtin_amdgcn_mfma_f32_16x16x32_bf16(
                        aF[rf], bF[cf], acc[rf][cf], 0, 0, 0);
        }

        // 3. seeds for NEXT iteration -- hidden under the s=1..3 MFMA stream
        {
            int nxt = (ii + 1 < ICHUNK) ? ii + 1 : ii;
            computeSeeds(nxt, sdN);
        }

        // 4. s=1..3 groups
        #pragma unroll
        for (int s = 1; s < 4; ++s) {
            short8 bF[8];
            #pragma unroll
            for (int cf = 0; cf < 8; ++cf)
                bF[cf] = __builtin_bit_cast(short8, Bimg[p][(s * 8 + cf) * 64 + l]);
            short8 aF[4];
            #pragma unroll
            for (int rf = 0; rf < 4; ++rf) aF[rf] = makeA(sdC[rf], s);
            #pragma unroll
            for (int rf = 0; rf < 4; ++rf)
                #pragma unroll
                for (int cf = 0; cf < 8; ++cf)
                    acc[rf][cf] = __builtin_amdgcn_mfma_f32_16x16x32_bf16(
                        aF[rf], bF[cf], acc[rf][cf], 0, 0, 0);
        }

        // 5. rotate seed buffers, barrier
        #pragma unroll
        for (int rf = 0; rf < 4; ++rf) sdC[rf] = sdN[rf];
        __syncthreads();
    }

    // epilogue: C/D layout col=l&15, row=(l>>4)*4+e
    const int r0 = rowBase + w * 64 + (l >> 4) * 4;
    const int c0 = by * 128 + m;
    if (PARTIAL) {
        unsigned short* dst = pws + (size_t)z * (4096u * 256u);
        #pragma unroll
        for (int rf = 0; rf < 4; ++rf)
            #pragma unroll
            for (int cf = 0; cf < 8; ++cf)
                #pragma unroll
                for (int e = 0; e < 4; ++e)
                    dst[(size_t)(r0 + rf * 16 + e) * 256 + (c0 + cf * 16)] =
                        f2bf(acc[rf][cf][e]);
    } else {
        #pragma unroll
        for (int rf = 0; rf < 4; ++rf)
            #pragma unroll
            for (int cf = 0; cf < 8; ++cf)
                #pragma unroll
                for (int e = 0; e < 4; ++e)
                    atomicAdd(out + (size_t)(r0 + rf * 16 + e) * 256 + (c0 + cf * 16),
                              acc[rf][cf][e]);
    }
}

extern "C" void kernel_launch(void* const* d_in, const int* in_sizes, int n_in,
                              void* d_out, int out_size, void* d_ws, size_t ws_size,
                              hipStream_t stream) {
    const float* x    = (const float*)d_in[0];
    const float* fc   = (const float*)d_in[1];
    const float* bias = (const float*)d_in[2];
    float* out = (float*)d_out;
    unsigned short* bws = (unsigned short*)d_ws;

    const size_t wsCoeff = (size_t)512 * 2048 * 16;                     // 16.78 MB
    const size_t wsFull  = wsCoeff + (size_t)SPLITK * 4096 * 256 * 2;   // +33.55 MB bf16 partials
    unsigned short* pws = (unsigned short*)((char*)d_ws + wsCoeff);

    if (ws_size >= wsFull) {
        hipLaunchKernelGGL(prep_kernel, dim3(4096), dim3(256), 0, stream,
                           fc, bias, bws, out, 0);
        hipLaunchKernelGGL((fkan_gemm<true, true>), dim3(256), dim3(512), 0, stream,
                           x, fc, bws, out, pws);
        hipLaunchKernelGGL(reduce_kernel, dim3(1024), dim3(256), 0, stream,
                           pws, bias, out);
    } else if (ws_size >= wsCoeff) {
        hipLaunchKernelGGL(prep_kernel, dim3(5120), dim3(256), 0, stream,
                           fc, bias, bws, out, 0);
        hipLaunchKernelGGL((fkan_gemm<true, false>), dim3(256), dim3(512), 0, stream,
                           x, fc, bws, out, pws);
    } else {
        hipLaunchKernelGGL(prep_kernel, dim3(1024), dim3(256), 0, stream,
                           fc, bias, bws, out, 4096);   // init out only
        hipLaunchKernelGGL((fkan_gemm<false, false>), dim3(256), dim3(512), 0, stream,
                           x, fc, bws, out, pws);
    }
}